// Round 2
// baseline (539.227 us; speedup 1.0000x reference)
//
#include <hip/hip_runtime.h>
#include <math.h>

// Problem constants (match reference)
#define B_N 4096
#define D_N 512
#define P_N 256
#define C_N 8

// workspace byte offsets
#define ACC_OFF   0                         // [0]=loss_sum, [1]=omega_sumsq
#define TP_OFF    1024                      // tp [P,D] f32
#define U_OFF     (TP_OFF + P_N*D_N*4)      // u  [P,D] f32
#define P2_OFF    (U_OFF + P_N*D_N*4)       // p2 [P] f32
#define X2_OFF    (P2_OFF + 4096)           // x2 [B,C] f32 (row-major [b][c])
#define DOTS_OFF  (X2_OFF + B_N*C_N*4)      // dots [B,P] f32

// K1a: tp[p,:] = Omega[label[p]] @ w[p]
__global__ void k_tp(const float* __restrict__ prot, const float* __restrict__ omega,
                     const int* __restrict__ labels, float* __restrict__ tp) {
    int p = blockIdx.x;
    int c = labels[p];
    const float* om = omega + (size_t)c * D_N * D_N;
    __shared__ float wsh[D_N];
    int t = threadIdx.x;
    wsh[t]       = prot[(size_t)p * D_N + t];
    wsh[t + 256] = prot[(size_t)p * D_N + t + 256];
    __syncthreads();
    int wave = t >> 6, lane = t & 63;
    for (int i = wave; i < D_N; i += 4) {
        const float4* row = (const float4*)(om + (size_t)i * D_N);
        float4 a = row[lane * 2];
        float4 b = row[lane * 2 + 1];
        int j = lane * 8;
        float partial = a.x * wsh[j]     + a.y * wsh[j + 1] + a.z * wsh[j + 2] + a.w * wsh[j + 3]
                      + b.x * wsh[j + 4] + b.y * wsh[j + 5] + b.z * wsh[j + 6] + b.w * wsh[j + 7];
        #pragma unroll
        for (int off = 32; off > 0; off >>= 1) partial += __shfl_down(partial, off);
        if (lane == 0) tp[(size_t)p * D_N + i] = partial;
    }
}

// K1b: u[p,:] = Omega[label[p]]^T @ tp[p,:] ; p2[p] = ||tp[p,:]||^2
__global__ void k_u_p2(const float* __restrict__ tp, const float* __restrict__ omega,
                       const int* __restrict__ labels, float* __restrict__ u,
                       float* __restrict__ p2) {
    int p = blockIdx.x;
    int c = labels[p];
    const float* om = omega + (size_t)c * D_N * D_N;
    __shared__ float tps[D_N];
    __shared__ float red[4];
    int t = threadIdx.x;
    float a0 = tp[(size_t)p * D_N + t];
    float a1 = tp[(size_t)p * D_N + t + 256];
    tps[t] = a0; tps[t + 256] = a1;
    float pp = a0 * a0 + a1 * a1;
    __syncthreads();
    #pragma unroll
    for (int off = 32; off > 0; off >>= 1) pp += __shfl_down(pp, off);
    if ((t & 63) == 0) red[t >> 6] = pp;

    float u0 = 0.f, u1 = 0.f;
    for (int i = 0; i < D_N; ++i) {
        float tv = tps[i];
        u0 += om[(size_t)i * D_N + t] * tv;
        u1 += om[(size_t)i * D_N + 256 + t] * tv;
    }
    u[(size_t)p * D_N + t]       = u0;
    u[(size_t)p * D_N + t + 256] = u1;
    __syncthreads();
    if (t == 0) p2[p] = red[0] + red[1] + red[2] + red[3];
}

// K2: x2[b,c] = ||Omega_c @ x_b||^2  — tiled GEMM with fused row-norm.
// grid (B/64, C), 256 threads, 64x64x64 tiles, 4x4 micro-tile per thread.
__global__ __launch_bounds__(256) void k_x2(const float* __restrict__ x,
                                            const float* __restrict__ omega,
                                            float* __restrict__ x2) {
    int b0 = blockIdx.x * 64;
    int c  = blockIdx.y;
    const float* om = omega + (size_t)c * D_N * D_N;
    __shared__ float Xt[64][68];  // [k][r] transposed
    __shared__ float Ot[64][68];  // [k][i] transposed
    __shared__ float red[64][17];
    int t = threadIdx.x;
    int tr = t >> 4, ti = t & 15;       // compute mapping
    int lr = t >> 4, lk = t & 15;       // load mapping
    float norm_part[4] = {0.f, 0.f, 0.f, 0.f};

    for (int i0 = 0; i0 < D_N; i0 += 64) {
        float acc[4][4] = {};
        for (int k0 = 0; k0 < D_N; k0 += 64) {
            __syncthreads();
            #pragma unroll
            for (int rr = 0; rr < 4; ++rr) {
                int r = lr + rr * 16;
                float4 v = *(const float4*)(x + (size_t)(b0 + r) * D_N + k0 + lk * 4);
                Xt[lk * 4 + 0][r] = v.x; Xt[lk * 4 + 1][r] = v.y;
                Xt[lk * 4 + 2][r] = v.z; Xt[lk * 4 + 3][r] = v.w;
                float4 w = *(const float4*)(om + (size_t)(i0 + r) * D_N + k0 + lk * 4);
                Ot[lk * 4 + 0][r] = w.x; Ot[lk * 4 + 1][r] = w.y;
                Ot[lk * 4 + 2][r] = w.z; Ot[lk * 4 + 3][r] = w.w;
            }
            __syncthreads();
            #pragma unroll 8
            for (int kk = 0; kk < 64; ++kk) {
                float4 xv = *(const float4*)&Xt[kk][tr * 4];
                float4 ov = *(const float4*)&Ot[kk][ti * 4];
                float xa[4] = {xv.x, xv.y, xv.z, xv.w};
                float oa[4] = {ov.x, ov.y, ov.z, ov.w};
                #pragma unroll
                for (int r2 = 0; r2 < 4; ++r2)
                    #pragma unroll
                    for (int ii = 0; ii < 4; ++ii)
                        acc[r2][ii] += xa[r2] * oa[ii];
            }
        }
        #pragma unroll
        for (int r2 = 0; r2 < 4; ++r2) {
            float s = 0.f;
            #pragma unroll
            for (int ii = 0; ii < 4; ++ii) s += acc[r2][ii] * acc[r2][ii];
            norm_part[r2] += s;
        }
    }
    __syncthreads();
    #pragma unroll
    for (int r2 = 0; r2 < 4; ++r2) red[tr * 4 + r2][ti] = norm_part[r2];
    __syncthreads();
    if (t < 64) {
        float s = 0.f;
        #pragma unroll
        for (int j = 0; j < 16; ++j) s += red[t][j];
        x2[(size_t)(b0 + t) * C_N + c] = s;
    }
}

// K3a: dots[b,p] = x_b . u_p — tiled GEMM, grid (B/64, P/64)
__global__ __launch_bounds__(256) void k_dots(const float* __restrict__ x,
                                              const float* __restrict__ u,
                                              float* __restrict__ dots) {
    int b0 = blockIdx.x * 64;
    int p0 = blockIdx.y * 64;
    __shared__ float Xt[64][68];
    __shared__ float Ut[64][68];
    int t = threadIdx.x;
    int tr = t >> 4, ti = t & 15;
    int lr = t >> 4, lk = t & 15;
    float acc[4][4] = {};
    for (int k0 = 0; k0 < D_N; k0 += 64) {
        __syncthreads();
        #pragma unroll
        for (int rr = 0; rr < 4; ++rr) {
            int r = lr + rr * 16;
            float4 v = *(const float4*)(x + (size_t)(b0 + r) * D_N + k0 + lk * 4);
            Xt[lk * 4 + 0][r] = v.x; Xt[lk * 4 + 1][r] = v.y;
            Xt[lk * 4 + 2][r] = v.z; Xt[lk * 4 + 3][r] = v.w;
            float4 w = *(const float4*)(u + (size_t)(p0 + r) * D_N + k0 + lk * 4);
            Ut[lk * 4 + 0][r] = w.x; Ut[lk * 4 + 1][r] = w.y;
            Ut[lk * 4 + 2][r] = w.z; Ut[lk * 4 + 3][r] = w.w;
        }
        __syncthreads();
        #pragma unroll 8
        for (int kk = 0; kk < 64; ++kk) {
            float4 xv = *(const float4*)&Xt[kk][tr * 4];
            float4 uv = *(const float4*)&Ut[kk][ti * 4];
            float xa[4] = {xv.x, xv.y, xv.z, xv.w};
            float ua[4] = {uv.x, uv.y, uv.z, uv.w};
            #pragma unroll
            for (int r2 = 0; r2 < 4; ++r2)
                #pragma unroll
                for (int ii = 0; ii < 4; ++ii)
                    acc[r2][ii] += xa[r2] * ua[ii];
        }
    }
    #pragma unroll
    for (int r2 = 0; r2 < 4; ++r2) {
        float4 st = make_float4(acc[r2][0], acc[r2][1], acc[r2][2], acc[r2][3]);
        *(float4*)(dots + (size_t)(b0 + tr * 4 + r2) * P_N + p0 + ti * 4) = st;
    }
}

// K3b: per-row pos/neg mins -> mu -> sigmoid -> partial sum (atomic)
__global__ void k_mu(const float* __restrict__ dots, const float* __restrict__ x2,
                     const float* __restrict__ p2, const int* __restrict__ labels,
                     const int* __restrict__ y, float* __restrict__ acc) {
    int t = threadIdx.x;
    int wave = t >> 6, lane = t & 63;
    int b = blockIdx.x * 4 + wave;
    __shared__ float red[4];
    int yb = y[b];
    float pos = INFINITY, neg = INFINITY;
    #pragma unroll
    for (int q = 0; q < 4; ++q) {
        int p = lane + q * 64;
        int lab = labels[p];
        float dist = x2[(size_t)b * C_N + lab] + p2[p]
                   - 2.f * dots[(size_t)b * P_N + p];
        if (lab == yb) pos = fminf(pos, dist);
        else           neg = fminf(neg, dist);
    }
    #pragma unroll
    for (int off = 32; off > 0; off >>= 1) {
        pos = fminf(pos, __shfl_xor(pos, off));
        neg = fminf(neg, __shfl_xor(neg, off));
    }
    if (lane == 0) {
        float mu = (pos - neg) / (pos + neg);
        red[wave] = 1.f / (1.f + expf(-mu));
    }
    __syncthreads();
    if (t == 0) atomicAdd(acc, red[0] + red[1] + red[2] + red[3]);
}

// K4: omega sum-of-squares
__global__ void k_oss(const float* __restrict__ omega, float* __restrict__ oss) {
    int idx = blockIdx.x * blockDim.x + threadIdx.x;
    const int total = C_N * D_N * D_N / 4;
    float s = 0.f;
    for (int i = idx; i < total; i += gridDim.x * blockDim.x) {
        float4 v = ((const float4*)omega)[i];
        s += v.x * v.x + v.y * v.y + v.z * v.z + v.w * v.w;
    }
    #pragma unroll
    for (int off = 32; off > 0; off >>= 1) s += __shfl_down(s, off);
    __shared__ float red[4];
    int t = threadIdx.x;
    if ((t & 63) == 0) red[t >> 6] = s;
    __syncthreads();
    if (t == 0) atomicAdd(oss, red[0] + red[1] + red[2] + red[3]);
}

// K5: finalize
__global__ void k_final(const float* __restrict__ accs, float* __restrict__ out) {
    out[0] = accs[0] * (1.f / (float)B_N) + 0.01f * sqrtf(accs[1]);
}

extern "C" void kernel_launch(void* const* d_in, const int* in_sizes, int n_in,
                              void* d_out, int out_size, void* d_ws, size_t ws_size,
                              hipStream_t stream) {
    (void)in_sizes; (void)n_in; (void)out_size; (void)ws_size;
    const float* x     = (const float*)d_in[0];
    const int*   y     = (const int*)d_in[1];
    const float* prot  = (const float*)d_in[2];
    const float* omega = (const float*)d_in[3];
    const int*   labels= (const int*)d_in[4];

    char* ws = (char*)d_ws;
    float* accs = (float*)(ws + ACC_OFF);   // [0]=loss_sum, [1]=omega_ss
    float* tp   = (float*)(ws + TP_OFF);
    float* u    = (float*)(ws + U_OFF);
    float* p2   = (float*)(ws + P2_OFF);
    float* x2   = (float*)(ws + X2_OFF);
    float* dots = (float*)(ws + DOTS_OFF);

    (void)hipMemsetAsync(accs, 0, 256, stream);
    k_tp  <<<P_N, 256, 0, stream>>>(prot, omega, labels, tp);
    k_u_p2<<<P_N, 256, 0, stream>>>(tp, omega, labels, u, p2);
    k_x2  <<<dim3(B_N / 64, C_N), 256, 0, stream>>>(x, omega, x2);
    k_dots<<<dim3(B_N / 64, P_N / 64), 256, 0, stream>>>(x, u, dots);
    k_mu  <<<B_N / 4, 256, 0, stream>>>(dots, x2, p2, labels, y, accs);
    k_oss <<<256, 256, 0, stream>>>(omega, accs + 1);
    k_final<<<1, 1, 0, stream>>>(accs, (float*)d_out);
}

// Round 3
// 163.775 us; speedup vs baseline: 3.2925x; 3.2925x over previous
//
#include <hip/hip_runtime.h>
#include <math.h>

typedef unsigned short ushort_t;
typedef __attribute__((ext_vector_type(8))) short short8;
typedef __attribute__((ext_vector_type(4))) float f32x4;

#define B_N 4096
#define D_N 512
#define P_N 256
#define C_N 8

// workspace byte offsets
#define ACC_OFF   0                          // [0]=loss_sum, [1]=omega_sumsq
#define P2G_OFF   256                        // p2 grouped [256] f32
#define X2_OFF    1280                       // x2 [B][C] f32
#define XB_OFF    132352                     // x bf16 [B][D]
#define OMB_OFF   (XB_OFF + B_N*D_N*2)       // omega bf16 [C][D][D]
#define TPG_OFF   (OMB_OFF + C_N*D_N*D_N*2)  // tp grouped bf16 [C][32][D]
#define UG_OFF    (TPG_OFF + P_N*D_N*2)      // u grouped bf16 [C][32][D]
#define OMBT_OFF  (UG_OFF + P_N*D_N*2)       // omega^T bf16 [C][D][D] (aliased w/ dots)
#define DOTS_OFF  OMBT_OFF                   // dots [B][256] f32 (after ombT is dead)

#define MFMA16(a, b, c) __builtin_amdgcn_mfma_f32_16x16x32_bf16(a, b, c, 0, 0, 0)

__device__ inline ushort_t f2bf(float f) {
    union { float f; unsigned u; } v; v.f = f;
    unsigned r = v.u + 0x7FFFu + ((v.u >> 16) & 1u);
    return (ushort_t)(r >> 16);
}

// ---------- cast x -> bf16 ----------
__global__ void k_cast_x(const float* __restrict__ x, ushort_t* __restrict__ xb) {
    int idx = blockIdx.x * 256 + threadIdx.x;            // 262144 threads, 8 elems each
    const float4* x4 = (const float4*)x;
    float4 a = x4[idx * 2], b = x4[idx * 2 + 1];
    union { ushort_t s[8]; uint4 v; } o;
    o.s[0] = f2bf(a.x); o.s[1] = f2bf(a.y); o.s[2] = f2bf(a.z); o.s[3] = f2bf(a.w);
    o.s[4] = f2bf(b.x); o.s[5] = f2bf(b.y); o.s[6] = f2bf(b.z); o.s[7] = f2bf(b.w);
    ((uint4*)xb)[idx] = o.v;
}

// ---------- cast omega -> bf16 (row-major + transposed) + sumsq ----------
__global__ void k_cast_om(const float* __restrict__ omega, ushort_t* __restrict__ omb,
                          ushort_t* __restrict__ ombT, float* __restrict__ oss) {
    int c = blockIdx.z, r0 = blockIdx.y * 64, c0 = blockIdx.x * 64;
    __shared__ ushort_t T[64][72];
    __shared__ float red[4];
    int t = threadIdx.x;
    int r = t >> 2, seg = t & 3;
    const float* src = omega + ((size_t)c * D_N + r0 + r) * D_N + c0 + seg * 16;
    float4 v0 = ((const float4*)src)[0], v1 = ((const float4*)src)[1];
    float4 v2 = ((const float4*)src)[2], v3 = ((const float4*)src)[3];
    float s = v0.x*v0.x + v0.y*v0.y + v0.z*v0.z + v0.w*v0.w
            + v1.x*v1.x + v1.y*v1.y + v1.z*v1.z + v1.w*v1.w
            + v2.x*v2.x + v2.y*v2.y + v2.z*v2.z + v2.w*v2.w
            + v3.x*v3.x + v3.y*v3.y + v3.z*v3.z + v3.w*v3.w;
    union { ushort_t s[16]; uint4 v[2]; } o;
    float vv[16] = {v0.x,v0.y,v0.z,v0.w, v1.x,v1.y,v1.z,v1.w,
                    v2.x,v2.y,v2.z,v2.w, v3.x,v3.y,v3.z,v3.w};
    #pragma unroll
    for (int j = 0; j < 16; ++j) o.s[j] = f2bf(vv[j]);
    uint4* dst = (uint4*)(omb + ((size_t)c * D_N + r0 + r) * D_N + c0 + seg * 16);
    dst[0] = o.v[0]; dst[1] = o.v[1];
    #pragma unroll
    for (int j = 0; j < 16; ++j) T[seg * 16 + j][r] = o.s[j];
    __syncthreads();
    // transposed write: ombT[c][c0+jr][r0 + seg*16 ..]
    int jr = t >> 2, sg2 = t & 3;
    uint4 w0 = *(uint4*)&T[jr][sg2 * 16];
    uint4 w1 = *(uint4*)&T[jr][sg2 * 16 + 8];
    uint4* dstT = (uint4*)(ombT + ((size_t)c * D_N + c0 + jr) * D_N + r0 + sg2 * 16);
    dstT[0] = w0; dstT[1] = w1;
    // sumsq reduce
    #pragma unroll
    for (int off = 32; off > 0; off >>= 1) s += __shfl_down(s, off);
    if ((t & 63) == 0) red[t >> 6] = s;
    __syncthreads();
    if (t == 0) atomicAdd(oss, red[0] + red[1] + red[2] + red[3]);
}

// ---------- tp[c*32+m][i] = sum_k prot[c+8m][k] * om_c[i][k]; p2 fused ----------
__global__ __launch_bounds__(256) void k_tp(const float* __restrict__ prot,
                                            const ushort_t* __restrict__ omb,
                                            ushort_t* __restrict__ tpg,
                                            float* __restrict__ p2g) {
    int i0 = blockIdx.x * 64, c = blockIdx.y;
    __shared__ ushort_t As[32][72];
    __shared__ ushort_t Bs[64][72];
    int t = threadIdx.x, w = t >> 6, lane = t & 63;
    int g = lane >> 4, cl = lane & 15;
    f32x4 acc[2] = {{0,0,0,0},{0,0,0,0}};
    for (int k0 = 0; k0 < D_N; k0 += 64) {
        __syncthreads();
        {   // stage A: prototypes fp32 -> bf16, rows m = t>>3, cols seg*8
            int m = t >> 3, seg = t & 7;
            const float* ap = prot + ((size_t)(c + 8 * m)) * D_N + k0 + seg * 8;
            float4 u0 = ((const float4*)ap)[0], u1 = ((const float4*)ap)[1];
            union { ushort_t s[8]; uint4 v; } o;
            o.s[0]=f2bf(u0.x); o.s[1]=f2bf(u0.y); o.s[2]=f2bf(u0.z); o.s[3]=f2bf(u0.w);
            o.s[4]=f2bf(u1.x); o.s[5]=f2bf(u1.y); o.s[6]=f2bf(u1.z); o.s[7]=f2bf(u1.w);
            *(uint4*)&As[m][seg * 8] = o.v;
        }
        {   // stage B: om_c rows i0+r, 2 chunks each
            int r = t >> 2, sg = t & 3;
            const uint4* bp = (const uint4*)(omb + ((size_t)c * D_N + i0 + r) * D_N + k0 + sg * 16);
            *(uint4*)&Bs[r][sg * 16] = bp[0];
            *(uint4*)&Bs[r][sg * 16 + 8] = bp[1];
        }
        __syncthreads();
        #pragma unroll
        for (int kk = 0; kk < 2; ++kk) {
            int koff = kk * 32 + g * 8;
            short8 bfr = *(const short8*)&Bs[w * 16 + cl][koff];
            #pragma unroll
            for (int mt = 0; mt < 2; ++mt) {
                short8 afr = *(const short8*)&As[mt * 16 + cl][koff];
                acc[mt] = MFMA16(afr, bfr, acc[mt]);
            }
        }
    }
    #pragma unroll
    for (int mt = 0; mt < 2; ++mt)
        #pragma unroll
        for (int reg = 0; reg < 4; ++reg) {
            float v = acc[mt][reg];
            int m = mt * 16 + g * 4 + reg;
            int i = i0 + w * 16 + cl;
            tpg[((size_t)c * 32 + m) * D_N + i] = f2bf(v);
            float s = v * v;
            s += __shfl_xor(s, 1); s += __shfl_xor(s, 2);
            s += __shfl_xor(s, 4); s += __shfl_xor(s, 8);
            if (cl == 0) atomicAdd(&p2g[c * 32 + m], s);
        }
}

// ---------- u[c*32+m][j] = sum_i tp[c*32+m][i] * om_c[i][j] (uses ombT) ----------
__global__ __launch_bounds__(256) void k_u(const ushort_t* __restrict__ tpg,
                                           const ushort_t* __restrict__ ombT,
                                           ushort_t* __restrict__ ug) {
    int j0 = blockIdx.x * 64, c = blockIdx.y;
    __shared__ ushort_t As[32][72];
    __shared__ ushort_t Bs[64][72];
    int t = threadIdx.x, w = t >> 6, lane = t & 63;
    int g = lane >> 4, cl = lane & 15;
    f32x4 acc[2] = {{0,0,0,0},{0,0,0,0}};
    for (int k0 = 0; k0 < D_N; k0 += 64) {
        __syncthreads();
        {
            int m = t >> 3, seg = t & 7;
            *(uint4*)&As[m][seg * 8] =
                *(const uint4*)(tpg + ((size_t)c * 32 + m) * D_N + k0 + seg * 8);
        }
        {
            int r = t >> 2, sg = t & 3;
            const uint4* bp = (const uint4*)(ombT + ((size_t)c * D_N + j0 + r) * D_N + k0 + sg * 16);
            *(uint4*)&Bs[r][sg * 16] = bp[0];
            *(uint4*)&Bs[r][sg * 16 + 8] = bp[1];
        }
        __syncthreads();
        #pragma unroll
        for (int kk = 0; kk < 2; ++kk) {
            int koff = kk * 32 + g * 8;
            short8 bfr = *(const short8*)&Bs[w * 16 + cl][koff];
            #pragma unroll
            for (int mt = 0; mt < 2; ++mt) {
                short8 afr = *(const short8*)&As[mt * 16 + cl][koff];
                acc[mt] = MFMA16(afr, bfr, acc[mt]);
            }
        }
    }
    #pragma unroll
    for (int mt = 0; mt < 2; ++mt)
        #pragma unroll
        for (int reg = 0; reg < 4; ++reg) {
            int m = mt * 16 + g * 4 + reg;
            int j = j0 + w * 16 + cl;
            ug[((size_t)c * 32 + m) * D_N + j] = f2bf(acc[mt][reg]);
        }
}

// ---------- x2[b][c] = ||om_c @ x_b||^2 — MFMA, fused row-norm ----------
// grid (B/128, C), 256 thr. 128x128 tile; wave quadrant 64x64 (4x4 frags).
__global__ __launch_bounds__(256) void k_x2(const ushort_t* __restrict__ xb,
                                            const ushort_t* __restrict__ omb,
                                            float* __restrict__ x2) {
    int b0 = blockIdx.x * 128, c = blockIdx.y;
    __shared__ ushort_t Xs[128][72];
    __shared__ ushort_t Os[128][72];
    __shared__ float red[128][2];
    int t = threadIdx.x, w = t >> 6, lane = t & 63;
    int qr = w >> 1, qc = w & 1;
    int g = lane >> 4, cl = lane & 15;
    float norm[4][4] = {};
    for (int i0 = 0; i0 < D_N; i0 += 128) {
        f32x4 acc[4][4];
        #pragma unroll
        for (int mt = 0; mt < 4; ++mt)
            #pragma unroll
            for (int nt = 0; nt < 4; ++nt) acc[mt][nt] = (f32x4){0,0,0,0};
        for (int k0 = 0; k0 < D_N; k0 += 64) {
            __syncthreads();
            {
                int r = t >> 1, h = t & 1;
                const uint4* xp = (const uint4*)(xb + (size_t)(b0 + r) * D_N + k0 + h * 32);
                uint4* xd = (uint4*)&Xs[r][h * 32];
                xd[0] = xp[0]; xd[1] = xp[1]; xd[2] = xp[2]; xd[3] = xp[3];
                const uint4* op = (const uint4*)(omb + ((size_t)c * D_N + i0 + r) * D_N + k0 + h * 32);
                uint4* od = (uint4*)&Os[r][h * 32];
                od[0] = op[0]; od[1] = op[1]; od[2] = op[2]; od[3] = op[3];
            }
            __syncthreads();
            #pragma unroll
            for (int kk = 0; kk < 2; ++kk) {
                int koff = kk * 32 + g * 8;
                short8 a[4], b[4];
                #pragma unroll
                for (int mt = 0; mt < 4; ++mt)
                    a[mt] = *(const short8*)&Xs[qr * 64 + mt * 16 + cl][koff];
                #pragma unroll
                for (int nt = 0; nt < 4; ++nt)
                    b[nt] = *(const short8*)&Os[qc * 64 + nt * 16 + cl][koff];
                #pragma unroll
                for (int mt = 0; mt < 4; ++mt)
                    #pragma unroll
                    for (int nt = 0; nt < 4; ++nt)
                        acc[mt][nt] = MFMA16(a[mt], b[nt], acc[mt][nt]);
            }
        }
        #pragma unroll
        for (int mt = 0; mt < 4; ++mt)
            #pragma unroll
            for (int nt = 0; nt < 4; ++nt)
                #pragma unroll
                for (int reg = 0; reg < 4; ++reg)
                    norm[mt][reg] += acc[mt][nt][reg] * acc[mt][nt][reg];
    }
    #pragma unroll
    for (int mt = 0; mt < 4; ++mt)
        #pragma unroll
        for (int reg = 0; reg < 4; ++reg) {
            float s = norm[mt][reg];
            s += __shfl_xor(s, 1); s += __shfl_xor(s, 2);
            s += __shfl_xor(s, 4); s += __shfl_xor(s, 8);
            if (cl == 0) red[qr * 64 + mt * 16 + g * 4 + reg][qc] = s;
        }
    __syncthreads();
    if (t < 128) x2[(size_t)(b0 + t) * C_N + c] = red[t][0] + red[t][1];
}

// ---------- dots[b][q] = x_b . u_q — MFMA, grid (B/64, 256/64) ----------
__global__ __launch_bounds__(256) void k_dots(const ushort_t* __restrict__ xb,
                                              const ushort_t* __restrict__ ug,
                                              float* __restrict__ dots) {
    int b0 = blockIdx.x * 64, q0 = blockIdx.y * 64;
    __shared__ ushort_t Xs[64][72];
    __shared__ ushort_t Us[64][72];
    int t = threadIdx.x, w = t >> 6, lane = t & 63;
    int qr = w >> 1, qc = w & 1;
    int g = lane >> 4, cl = lane & 15;
    f32x4 acc[2][2];
    #pragma unroll
    for (int mt = 0; mt < 2; ++mt)
        #pragma unroll
        for (int nt = 0; nt < 2; ++nt) acc[mt][nt] = (f32x4){0,0,0,0};
    for (int k0 = 0; k0 < D_N; k0 += 64) {
        __syncthreads();
        {
            int r = t >> 2, sg = t & 3;
            const uint4* xp = (const uint4*)(xb + (size_t)(b0 + r) * D_N + k0 + sg * 16);
            *(uint4*)&Xs[r][sg * 16] = xp[0];
            *(uint4*)&Xs[r][sg * 16 + 8] = xp[1];
            const uint4* up = (const uint4*)(ug + (size_t)(q0 + r) * D_N + k0 + sg * 16);
            *(uint4*)&Us[r][sg * 16] = up[0];
            *(uint4*)&Us[r][sg * 16 + 8] = up[1];
        }
        __syncthreads();
        #pragma unroll
        for (int kk = 0; kk < 2; ++kk) {
            int koff = kk * 32 + g * 8;
            short8 a[2], b[2];
            #pragma unroll
            for (int mt = 0; mt < 2; ++mt)
                a[mt] = *(const short8*)&Xs[qr * 32 + mt * 16 + cl][koff];
            #pragma unroll
            for (int nt = 0; nt < 2; ++nt)
                b[nt] = *(const short8*)&Us[qc * 32 + nt * 16 + cl][koff];
            #pragma unroll
            for (int mt = 0; mt < 2; ++mt)
                #pragma unroll
                for (int nt = 0; nt < 2; ++nt)
                    acc[mt][nt] = MFMA16(a[mt], b[nt], acc[mt][nt]);
        }
    }
    #pragma unroll
    for (int mt = 0; mt < 2; ++mt)
        #pragma unroll
        for (int nt = 0; nt < 2; ++nt)
            #pragma unroll
            for (int reg = 0; reg < 4; ++reg) {
                int b = b0 + qr * 32 + mt * 16 + g * 4 + reg;
                int q = q0 + qc * 32 + nt * 16 + cl;
                dots[(size_t)b * P_N + q] = acc[mt][nt][reg];
            }
}

// ---------- per-row mins -> mu -> sigmoid -> sum ----------
__global__ void k_mu(const float* __restrict__ dots, const float* __restrict__ x2,
                     const float* __restrict__ p2g, const int* __restrict__ y,
                     float* __restrict__ acc) {
    int t = threadIdx.x, w = t >> 6, lane = t & 63;
    int b = blockIdx.x * 4 + w;
    __shared__ float red[4];
    int yb = y[b];
    float pos = INFINITY, neg = INFINITY;
    #pragma unroll
    for (int j = 0; j < 4; ++j) {
        int q = lane + j * 64;
        int lab = q >> 5;
        float dist = x2[(size_t)b * C_N + lab] + p2g[q] - 2.f * dots[(size_t)b * P_N + q];
        if (lab == yb) pos = fminf(pos, dist);
        else           neg = fminf(neg, dist);
    }
    #pragma unroll
    for (int off = 32; off > 0; off >>= 1) {
        pos = fminf(pos, __shfl_xor(pos, off));
        neg = fminf(neg, __shfl_xor(neg, off));
    }
    if (lane == 0) {
        float mu = (pos - neg) / (pos + neg);
        red[w] = 1.f / (1.f + expf(-mu));
    }
    __syncthreads();
    if (t == 0) atomicAdd(acc, red[0] + red[1] + red[2] + red[3]);
}

__global__ void k_final(const float* __restrict__ accs, float* __restrict__ out) {
    out[0] = accs[0] * (1.f / (float)B_N) + 0.01f * sqrtf(accs[1]);
}

extern "C" void kernel_launch(void* const* d_in, const int* in_sizes, int n_in,
                              void* d_out, int out_size, void* d_ws, size_t ws_size,
                              hipStream_t stream) {
    (void)in_sizes; (void)n_in; (void)out_size; (void)ws_size;
    const float* x     = (const float*)d_in[0];
    const int*   y     = (const int*)d_in[1];
    const float* prot  = (const float*)d_in[2];
    const float* omega = (const float*)d_in[3];

    char* ws = (char*)d_ws;
    float*    accs = (float*)(ws + ACC_OFF);
    float*    p2g  = (float*)(ws + P2G_OFF);
    float*    x2   = (float*)(ws + X2_OFF);
    ushort_t* xb   = (ushort_t*)(ws + XB_OFF);
    ushort_t* omb  = (ushort_t*)(ws + OMB_OFF);
    ushort_t* tpg  = (ushort_t*)(ws + TPG_OFF);
    ushort_t* ug   = (ushort_t*)(ws + UG_OFF);
    ushort_t* ombT = (ushort_t*)(ws + OMBT_OFF);
    float*    dots = (float*)(ws + DOTS_OFF);

    (void)hipMemsetAsync(ws, 0, 1280, stream);
    k_cast_x <<<B_N * D_N / 8 / 256, 256, 0, stream>>>(x, xb);
    k_cast_om<<<dim3(8, 8, C_N), 256, 0, stream>>>(omega, omb, ombT, accs + 1);
    k_tp     <<<dim3(8, C_N), 256, 0, stream>>>(prot, omb, tpg, p2g);
    k_u      <<<dim3(8, C_N), 256, 0, stream>>>(tpg, ombT, ug);
    k_x2     <<<dim3(B_N / 128, C_N), 256, 0, stream>>>(xb, omb, x2);
    k_dots   <<<dim3(B_N / 64, P_N / 64), 256, 0, stream>>>(xb, ug, dots);
    k_mu     <<<B_N / 4, 256, 0, stream>>>(dots, x2, p2g, y, accs);
    k_final  <<<1, 1, 0, stream>>>(accs, (float*)d_out);
}

// Round 4
// 143.744 us; speedup vs baseline: 3.7513x; 1.1393x over previous
//
#include <hip/hip_runtime.h>
#include <math.h>

typedef unsigned short ushort_t;
typedef __attribute__((ext_vector_type(8))) short short8;
typedef __attribute__((ext_vector_type(4))) float f32x4;

#define B_N 4096
#define D_N 512
#define P_N 256
#define C_N 8

// workspace byte offsets
#define ACC_OFF   0                          // [0]=loss_sum, [1]=omega_sumsq
#define P2G_OFF   256                        // p2 grouped [256] f32
#define X2_OFF    1280                       // x2 [B][C] f32 (atomically accumulated)
#define XB_OFF    132352                     // x bf16 [B][D]
#define OMB_OFF   (XB_OFF + B_N*D_N*2)       // omega bf16 [C][D][D]
#define TPG_OFF   (OMB_OFF + C_N*D_N*D_N*2)  // tp grouped bf16 [C][32][D]
#define UG_OFF    (TPG_OFF + P_N*D_N*2)      // u grouped bf16 [C][32][D]
#define OMBT_OFF  (UG_OFF + P_N*D_N*2)       // omega^T bf16 [C][D][D]

#define MFMA16(a, b, c) __builtin_amdgcn_mfma_f32_16x16x32_bf16(a, b, c, 0, 0, 0)

__device__ inline ushort_t f2bf(float f) {
    union { float f; unsigned u; } v; v.f = f;
    unsigned r = v.u + 0x7FFFu + ((v.u >> 16) & 1u);
    return (ushort_t)(r >> 16);
}

// ---------- cast x -> bf16 ----------
__global__ void k_cast_x(const float* __restrict__ x, ushort_t* __restrict__ xb) {
    int idx = blockIdx.x * 256 + threadIdx.x;
    const float4* x4 = (const float4*)x;
    float4 a = x4[idx * 2], b = x4[idx * 2 + 1];
    union { ushort_t s[8]; uint4 v; } o;
    o.s[0] = f2bf(a.x); o.s[1] = f2bf(a.y); o.s[2] = f2bf(a.z); o.s[3] = f2bf(a.w);
    o.s[4] = f2bf(b.x); o.s[5] = f2bf(b.y); o.s[6] = f2bf(b.z); o.s[7] = f2bf(b.w);
    ((uint4*)xb)[idx] = o.v;
}

// ---------- cast omega -> bf16 (row-major + transposed) + sumsq ----------
__global__ void k_cast_om(const float* __restrict__ omega, ushort_t* __restrict__ omb,
                          ushort_t* __restrict__ ombT, float* __restrict__ oss) {
    int c = blockIdx.z, r0 = blockIdx.y * 64, c0 = blockIdx.x * 64;
    __shared__ ushort_t T[64][72];
    __shared__ float red[4];
    int t = threadIdx.x;
    int r = t >> 2, seg = t & 3;
    const float* src = omega + ((size_t)c * D_N + r0 + r) * D_N + c0 + seg * 16;
    float4 v0 = ((const float4*)src)[0], v1 = ((const float4*)src)[1];
    float4 v2 = ((const float4*)src)[2], v3 = ((const float4*)src)[3];
    float s = v0.x*v0.x + v0.y*v0.y + v0.z*v0.z + v0.w*v0.w
            + v1.x*v1.x + v1.y*v1.y + v1.z*v1.z + v1.w*v1.w
            + v2.x*v2.x + v2.y*v2.y + v2.z*v2.z + v2.w*v2.w
            + v3.x*v3.x + v3.y*v3.y + v3.z*v3.z + v3.w*v3.w;
    union { ushort_t s[16]; uint4 v[2]; } o;
    float vv[16] = {v0.x,v0.y,v0.z,v0.w, v1.x,v1.y,v1.z,v1.w,
                    v2.x,v2.y,v2.z,v2.w, v3.x,v3.y,v3.z,v3.w};
    #pragma unroll
    for (int j = 0; j < 16; ++j) o.s[j] = f2bf(vv[j]);
    uint4* dst = (uint4*)(omb + ((size_t)c * D_N + r0 + r) * D_N + c0 + seg * 16);
    dst[0] = o.v[0]; dst[1] = o.v[1];
    #pragma unroll
    for (int j = 0; j < 16; ++j) T[seg * 16 + j][r] = o.s[j];
    __syncthreads();
    int jr = t >> 2, sg2 = t & 3;
    uint4 w0 = *(uint4*)&T[jr][sg2 * 16];
    uint4 w1 = *(uint4*)&T[jr][sg2 * 16 + 8];
    uint4* dstT = (uint4*)(ombT + ((size_t)c * D_N + c0 + jr) * D_N + r0 + sg2 * 16);
    dstT[0] = w0; dstT[1] = w1;
    #pragma unroll
    for (int off = 32; off > 0; off >>= 1) s += __shfl_down(s, off);
    if ((t & 63) == 0) red[t >> 6] = s;
    __syncthreads();
    if (t == 0) atomicAdd(oss, red[0] + red[1] + red[2] + red[3]);
}

// ---------- tp[c*32+m][i] = sum_k prot[c+8m][k] * om_c[i][k]; p2 fused ----------
__global__ __launch_bounds__(256) void k_tp(const float* __restrict__ prot,
                                            const ushort_t* __restrict__ omb,
                                            ushort_t* __restrict__ tpg,
                                            float* __restrict__ p2g) {
    int i0 = blockIdx.x * 64, c = blockIdx.y;
    __shared__ ushort_t As[32][72];
    __shared__ ushort_t Bs[64][72];
    int t = threadIdx.x, w = t >> 6, lane = t & 63;
    int g = lane >> 4, cl = lane & 15;
    f32x4 acc[2] = {{0,0,0,0},{0,0,0,0}};
    for (int k0 = 0; k0 < D_N; k0 += 64) {
        __syncthreads();
        {
            int m = t >> 3, seg = t & 7;
            const float* ap = prot + ((size_t)(c + 8 * m)) * D_N + k0 + seg * 8;
            float4 u0 = ((const float4*)ap)[0], u1 = ((const float4*)ap)[1];
            union { ushort_t s[8]; uint4 v; } o;
            o.s[0]=f2bf(u0.x); o.s[1]=f2bf(u0.y); o.s[2]=f2bf(u0.z); o.s[3]=f2bf(u0.w);
            o.s[4]=f2bf(u1.x); o.s[5]=f2bf(u1.y); o.s[6]=f2bf(u1.z); o.s[7]=f2bf(u1.w);
            *(uint4*)&As[m][seg * 8] = o.v;
        }
        {
            int r = t >> 2, sg = t & 3;
            const uint4* bp = (const uint4*)(omb + ((size_t)c * D_N + i0 + r) * D_N + k0 + sg * 16);
            *(uint4*)&Bs[r][sg * 16] = bp[0];
            *(uint4*)&Bs[r][sg * 16 + 8] = bp[1];
        }
        __syncthreads();
        #pragma unroll
        for (int kk = 0; kk < 2; ++kk) {
            int koff = kk * 32 + g * 8;
            short8 bfr = *(const short8*)&Bs[w * 16 + cl][koff];
            #pragma unroll
            for (int mt = 0; mt < 2; ++mt) {
                short8 afr = *(const short8*)&As[mt * 16 + cl][koff];
                acc[mt] = MFMA16(afr, bfr, acc[mt]);
            }
        }
    }
    #pragma unroll
    for (int mt = 0; mt < 2; ++mt)
        #pragma unroll
        for (int reg = 0; reg < 4; ++reg) {
            float v = acc[mt][reg];
            int m = mt * 16 + g * 4 + reg;
            int i = i0 + w * 16 + cl;
            tpg[((size_t)c * 32 + m) * D_N + i] = f2bf(v);
            float s = v * v;
            s += __shfl_xor(s, 1); s += __shfl_xor(s, 2);
            s += __shfl_xor(s, 4); s += __shfl_xor(s, 8);
            if (cl == 0) atomicAdd(&p2g[c * 32 + m], s);
        }
}

// ---------- u[c*32+m][j] = sum_i tp[c*32+m][i] * om_c[i][j] (uses ombT) ----------
__global__ __launch_bounds__(256) void k_u(const ushort_t* __restrict__ tpg,
                                           const ushort_t* __restrict__ ombT,
                                           ushort_t* __restrict__ ug) {
    int j0 = blockIdx.x * 64, c = blockIdx.y;
    __shared__ ushort_t As[32][72];
    __shared__ ushort_t Bs[64][72];
    int t = threadIdx.x, w = t >> 6, lane = t & 63;
    int g = lane >> 4, cl = lane & 15;
    f32x4 acc[2] = {{0,0,0,0},{0,0,0,0}};
    for (int k0 = 0; k0 < D_N; k0 += 64) {
        __syncthreads();
        {
            int m = t >> 3, seg = t & 7;
            *(uint4*)&As[m][seg * 8] =
                *(const uint4*)(tpg + ((size_t)c * 32 + m) * D_N + k0 + seg * 8);
        }
        {
            int r = t >> 2, sg = t & 3;
            const uint4* bp = (const uint4*)(ombT + ((size_t)c * D_N + j0 + r) * D_N + k0 + sg * 16);
            *(uint4*)&Bs[r][sg * 16] = bp[0];
            *(uint4*)&Bs[r][sg * 16 + 8] = bp[1];
        }
        __syncthreads();
        #pragma unroll
        for (int kk = 0; kk < 2; ++kk) {
            int koff = kk * 32 + g * 8;
            short8 bfr = *(const short8*)&Bs[w * 16 + cl][koff];
            #pragma unroll
            for (int mt = 0; mt < 2; ++mt) {
                short8 afr = *(const short8*)&As[mt * 16 + cl][koff];
                acc[mt] = MFMA16(afr, bfr, acc[mt]);
            }
        }
    }
    #pragma unroll
    for (int mt = 0; mt < 2; ++mt)
        #pragma unroll
        for (int reg = 0; reg < 4; ++reg) {
            int m = mt * 16 + g * 4 + reg;
            int j = j0 + w * 16 + cl;
            ug[((size_t)c * 32 + m) * D_N + j] = f2bf(acc[mt][reg]);
        }
}

// ---------- x2 partial: block (i-chunk, c, b-chunk) adds ||om_c[i0:i0+128] x_b||^2 ----------
// grid (4, 8, 32), 256 thr, 4 blocks/CU. 128x128 tile; wave quadrant 64x64.
__global__ __launch_bounds__(256, 4) void k_x2(const ushort_t* __restrict__ xb,
                                               const ushort_t* __restrict__ omb,
                                               float* __restrict__ x2) {
    int i0 = blockIdx.x * 128;
    int c  = blockIdx.y;
    int b0 = blockIdx.z * 128;
    __shared__ ushort_t Xs[128][72];
    __shared__ ushort_t Os[128][72];
    __shared__ float red[128][2];
    int t = threadIdx.x, w = t >> 6, lane = t & 63;
    int qr = w >> 1, qc = w & 1;
    int g = lane >> 4, cl = lane & 15;
    f32x4 acc[4][4];
    #pragma unroll
    for (int mt = 0; mt < 4; ++mt)
        #pragma unroll
        for (int nt = 0; nt < 4; ++nt) acc[mt][nt] = (f32x4){0,0,0,0};
    for (int k0 = 0; k0 < D_N; k0 += 64) {
        __syncthreads();
        {
            int r = t >> 1, h = t & 1;
            const uint4* xp = (const uint4*)(xb + (size_t)(b0 + r) * D_N + k0 + h * 32);
            uint4* xd = (uint4*)&Xs[r][h * 32];
            xd[0] = xp[0]; xd[1] = xp[1]; xd[2] = xp[2]; xd[3] = xp[3];
            const uint4* op = (const uint4*)(omb + ((size_t)c * D_N + i0 + r) * D_N + k0 + h * 32);
            uint4* od = (uint4*)&Os[r][h * 32];
            od[0] = op[0]; od[1] = op[1]; od[2] = op[2]; od[3] = op[3];
        }
        __syncthreads();
        #pragma unroll
        for (int kk = 0; kk < 2; ++kk) {
            int koff = kk * 32 + g * 8;
            short8 a[4], b[4];
            #pragma unroll
            for (int mt = 0; mt < 4; ++mt)
                a[mt] = *(const short8*)&Xs[qr * 64 + mt * 16 + cl][koff];
            #pragma unroll
            for (int nt = 0; nt < 4; ++nt)
                b[nt] = *(const short8*)&Os[qc * 64 + nt * 16 + cl][koff];
            #pragma unroll
            for (int mt = 0; mt < 4; ++mt)
                #pragma unroll
                for (int nt = 0; nt < 4; ++nt)
                    acc[mt][nt] = MFMA16(a[mt], b[nt], acc[mt][nt]);
        }
    }
    #pragma unroll
    for (int mt = 0; mt < 4; ++mt)
        #pragma unroll
        for (int reg = 0; reg < 4; ++reg) {
            float s = 0.f;
            #pragma unroll
            for (int nt = 0; nt < 4; ++nt) s += acc[mt][nt][reg] * acc[mt][nt][reg];
            s += __shfl_xor(s, 1); s += __shfl_xor(s, 2);
            s += __shfl_xor(s, 4); s += __shfl_xor(s, 8);
            if (cl == 0) red[qr * 64 + mt * 16 + g * 4 + reg][qc] = s;
        }
    __syncthreads();
    if (t < 128) atomicAdd(&x2[(size_t)(b0 + t) * C_N + c], red[t][0] + red[t][1]);
}

// ---------- fused dots + min + mu + sigmoid + sum ----------
// grid B/16 = 256 blocks, 256 thr. Block: 16 b-rows x all 256 q. Wave w: q in [64w, 64w+64).
__global__ __launch_bounds__(256) void k_dm(const ushort_t* __restrict__ xb,
                                            const ushort_t* __restrict__ ug,
                                            const float* __restrict__ x2,
                                            const float* __restrict__ p2g,
                                            const int* __restrict__ y,
                                            float* __restrict__ acc_out) {
    int b0 = blockIdx.x * 16;
    __shared__ ushort_t Xs[16][72];
    __shared__ ushort_t Us[256][72];
    __shared__ float mind[16][8];
    __shared__ float smu[16];
    int t = threadIdx.x, w = t >> 6, lane = t & 63;
    int g = lane >> 4, cl = lane & 15;
    f32x4 acc[4];
    #pragma unroll
    for (int nt = 0; nt < 4; ++nt) acc[nt] = (f32x4){0,0,0,0};
    for (int k0 = 0; k0 < D_N; k0 += 64) {
        __syncthreads();
        if (t < 128) {
            int r = t >> 3, seg = t & 7;
            *(uint4*)&Xs[r][seg * 8] = *(const uint4*)(xb + (size_t)(b0 + r) * D_N + k0 + seg * 8);
        }
        #pragma unroll
        for (int j = 0; j < 8; ++j) {
            int idx = j * 256 + t;
            int r = idx >> 3, cu = idx & 7;
            *(uint4*)&Us[r][cu * 8] = *(const uint4*)(ug + (size_t)r * D_N + k0 + cu * 8);
        }
        __syncthreads();
        #pragma unroll
        for (int kk = 0; kk < 2; ++kk) {
            int koff = kk * 32 + g * 8;
            short8 a = *(const short8*)&Xs[cl][koff];
            #pragma unroll
            for (int nt = 0; nt < 4; ++nt) {
                short8 b = *(const short8*)&Us[w * 64 + nt * 16 + cl][koff];
                acc[nt] = MFMA16(a, b, acc[nt]);
            }
        }
    }
    // dist -> per-(row,class-pair) min
    float mn[2][4];
    #pragma unroll
    for (int cls = 0; cls < 2; ++cls)
        #pragma unroll
        for (int reg = 0; reg < 4; ++reg) mn[cls][reg] = INFINITY;
    #pragma unroll
    for (int nt = 0; nt < 4; ++nt) {
        int q = w * 64 + nt * 16 + cl;
        int cls = nt >> 1;
        float pq = p2g[q];
        #pragma unroll
        for (int reg = 0; reg < 4; ++reg) {
            int b = b0 + g * 4 + reg;
            float dist = x2[(size_t)b * C_N + 2 * w + cls] + pq - 2.f * acc[nt][reg];
            mn[cls][reg] = fminf(mn[cls][reg], dist);
        }
    }
    #pragma unroll
    for (int cls = 0; cls < 2; ++cls)
        #pragma unroll
        for (int reg = 0; reg < 4; ++reg) {
            float v = mn[cls][reg];
            v = fminf(v, __shfl_xor(v, 1)); v = fminf(v, __shfl_xor(v, 2));
            v = fminf(v, __shfl_xor(v, 4)); v = fminf(v, __shfl_xor(v, 8));
            if (cl == 0) mind[g * 4 + reg][2 * w + cls] = v;
        }
    __syncthreads();
    if (t < 16) {
        int yb = y[b0 + t];
        float pos = mind[t][yb];
        float neg = INFINITY;
        #pragma unroll
        for (int cc = 0; cc < 8; ++cc)
            if (cc != yb) neg = fminf(neg, mind[t][cc]);
        float mu = (pos - neg) / (pos + neg);
        smu[t] = 1.f / (1.f + expf(-mu));
    }
    __syncthreads();
    if (t == 0) {
        float s = 0.f;
        #pragma unroll
        for (int j = 0; j < 16; ++j) s += smu[j];
        atomicAdd(acc_out, s);
    }
}

__global__ void k_final(const float* __restrict__ accs, float* __restrict__ out) {
    out[0] = accs[0] * (1.f / (float)B_N) + 0.01f * sqrtf(accs[1]);
}

extern "C" void kernel_launch(void* const* d_in, const int* in_sizes, int n_in,
                              void* d_out, int out_size, void* d_ws, size_t ws_size,
                              hipStream_t stream) {
    (void)in_sizes; (void)n_in; (void)out_size; (void)ws_size;
    const float* x     = (const float*)d_in[0];
    const int*   y     = (const int*)d_in[1];
    const float* prot  = (const float*)d_in[2];
    const float* omega = (const float*)d_in[3];

    char* ws = (char*)d_ws;
    float*    accs = (float*)(ws + ACC_OFF);
    float*    p2g  = (float*)(ws + P2G_OFF);
    float*    x2   = (float*)(ws + X2_OFF);
    ushort_t* xb   = (ushort_t*)(ws + XB_OFF);
    ushort_t* omb  = (ushort_t*)(ws + OMB_OFF);
    ushort_t* tpg  = (ushort_t*)(ws + TPG_OFF);
    ushort_t* ug   = (ushort_t*)(ws + UG_OFF);
    ushort_t* ombT = (ushort_t*)(ws + OMBT_OFF);

    (void)hipMemsetAsync(ws, 0, XB_OFF, stream);  // accs, p2g, x2
    k_cast_x <<<B_N * D_N / 8 / 256, 256, 0, stream>>>(x, xb);
    k_cast_om<<<dim3(8, 8, C_N), 256, 0, stream>>>(omega, omb, ombT, accs + 1);
    k_tp     <<<dim3(8, C_N), 256, 0, stream>>>(prot, omb, tpg, p2g);
    k_u      <<<dim3(8, C_N), 256, 0, stream>>>(tpg, ombT, ug);
    k_x2     <<<dim3(4, C_N, B_N / 128), 256, 0, stream>>>(xb, omb, x2);
    k_dm     <<<B_N / 16, 256, 0, stream>>>(xb, ug, x2, p2g, y, accs);
    k_final  <<<1, 1, 0, stream>>>(accs, (float*)d_out);
}